// Round 1
// baseline (289.762 us; speedup 1.0000x reference)
//
#include <hip/hip_runtime.h>

#define WS   7
#define NH   8
#define HD   32          // head dim = C / NH
#define WIN  49          // WS*WS
#define HALO 9           // WS + 2
#define VST  33          // padded pixel stride for v-halo (bank-conflict-free lepe reads)

__global__ __launch_bounds__(64)
void win_attn_lepe(const float* __restrict__ qkv,
                   const float* __restrict__ lw,
                   const float* __restrict__ lb,
                   float* __restrict__ out,
                   int B, int H, int W, int C)
{
    const int N  = H * W;
    const int Gw = W / WS;
    const int Gh = H / WS;

    const int wid = blockIdx.x;          // window id in [0, B*Gh*Gw)
    const int h   = blockIdx.y;          // head
    const int b   = wid / (Gh * Gw);
    const int g   = wid % (Gh * Gw);
    const int gy  = g / Gw, gx = g % Gw;
    const int row0 = gy * WS, col0 = gx * WS;
    const int c0   = h * HD;

    const size_t plane = (size_t)B * N * C;
    const float* q_base = qkv + (size_t)b * N * C;
    const float* k_base = q_base + plane;
    const float* v_base = q_base + 2 * plane;

    __shared__ float sK[WIN * HD];            // K window [49][32]
    __shared__ float sV[HALO * HALO * VST];   // V halo   [81][33]
    __shared__ float sW[HD * 9];              // lepe weights for this head's 32 channels
    __shared__ float sB[HD];

    const int tid = threadIdx.x;

    // ---- stage K window: 392 float4s, coalesced-ish (8 lanes per token, 128B segs) ----
    for (int f4 = tid; f4 < WIN * HD / 4; f4 += 64) {
        int n  = f4 >> 3;                 // token in window
        int d4 = (f4 & 7) * 4;
        int r = row0 + n / WS, c = col0 + n % WS;
        float4 kv = *reinterpret_cast<const float4*>(k_base + ((size_t)r * W + c) * C + c0 + d4);
        *reinterpret_cast<float4*>(&sK[n * HD + d4]) = kv;
    }

    // ---- stage V halo: 81 pixels x 32 ch, zero-padded at image boundary ----
    for (int p = tid; p < HALO * HALO; p += 64) {
        int ry = row0 - 1 + p / HALO;
        int rx = col0 - 1 + p % HALO;
        bool in = (ry >= 0 && ry < H && rx >= 0 && rx < W);
        const float* src = v_base + ((size_t)ry * W + rx) * C + c0;
        float* dst = &sV[p * VST];
        #pragma unroll
        for (int d = 0; d < HD; d += 4) {
            float4 vv = in ? *reinterpret_cast<const float4*>(src + d)
                           : make_float4(0.f, 0.f, 0.f, 0.f);
            dst[d + 0] = vv.x; dst[d + 1] = vv.y; dst[d + 2] = vv.z; dst[d + 3] = vv.w;
        }
    }

    // ---- stage lepe weights + bias for this head's channels ----
    for (int i = tid; i < HD * 9; i += 64) sW[i] = lw[(size_t)(c0 + i / 9) * 9 + i % 9];
    if (tid < HD) sB[tid] = lb[c0 + tid];

    __syncthreads();

    if (tid < WIN) {
        const int wy = tid / WS, wx = tid % WS;
        const int r = row0 + wy, c = col0 + wx;

        // q into registers, pre-scaled
        const float scale = 0.17677669529663687f;   // 32^-0.5
        float qreg[HD];
        const float* qp = q_base + ((size_t)r * W + c) * C + c0;
        #pragma unroll
        for (int d = 0; d < HD; d += 4) {
            float4 t4 = *reinterpret_cast<const float4*>(qp + d);
            qreg[d] = t4.x * scale; qreg[d+1] = t4.y * scale;
            qreg[d+2] = t4.z * scale; qreg[d+3] = t4.w * scale;
        }

        // scores: s[m] = q . k_m   (sK reads are wave-uniform -> broadcast, no conflicts)
        float s[WIN];
        #pragma unroll
        for (int m = 0; m < WIN; ++m) {
            float acc = 0.f;
            #pragma unroll
            for (int d = 0; d < HD; ++d) acc += qreg[d] * sK[m * HD + d];
            s[m] = acc;
        }

        // softmax (fully lane-local)
        float mx = s[0];
        #pragma unroll
        for (int m = 1; m < WIN; ++m) mx = fmaxf(mx, s[m]);
        float sum = 0.f;
        #pragma unroll
        for (int m = 0; m < WIN; ++m) { s[m] = __expf(s[m] - mx); sum += s[m]; }
        const float inv = 1.f / sum;

        // out = P @ V  (broadcast reads from halo, window pixel (my,mx) -> halo (my+1,mx+1))
        float o[HD];
        #pragma unroll
        for (int d = 0; d < HD; ++d) o[d] = 0.f;
        #pragma unroll
        for (int m = 0; m < WIN; ++m) {
            float pm = s[m] * inv;
            const float* vrow = &sV[(size_t)((m / WS + 1) * HALO + (m % WS + 1)) * VST];
            #pragma unroll
            for (int d = 0; d < HD; ++d) o[d] += pm * vrow[d];
        }

        // lepe: depthwise 3x3 (cross-correlation) + bias, read from padded halo
        #pragma unroll
        for (int d = 0; d < HD; ++d) {
            float acc = sB[d];
            #pragma unroll
            for (int dh = 0; dh < 3; ++dh)
                #pragma unroll
                for (int dw = 0; dw < 3; ++dw)
                    acc += sW[d * 9 + dh * 3 + dw] * sV[((wy + dh) * HALO + (wx + dw)) * VST + d];
            o[d] += acc;
        }

        // write out[b, r*W+c, c0..c0+31]
        float* dst = out + ((size_t)b * N + (size_t)r * W + c) * C + c0;
        #pragma unroll
        for (int d = 0; d < HD; d += 4) {
            float4 t4 = make_float4(o[d], o[d+1], o[d+2], o[d+3]);
            *reinterpret_cast<float4*>(dst + d) = t4;
        }
    }
}

extern "C" void kernel_launch(void* const* d_in, const int* in_sizes, int n_in,
                              void* d_out, int out_size, void* d_ws, size_t ws_size,
                              hipStream_t stream) {
    const float* qkv = (const float*)d_in[0];
    const float* lw  = (const float*)d_in[1];
    const float* lb  = (const float*)d_in[2];
    float* out = (float*)d_out;

    // setup_inputs(): B=8, H=W=112, C=256 (H,W live on device; fixed by the reference setup)
    const int H = 112, W = 112;
    const int C = in_sizes[2];                 // lepe_b has C elements
    const int N = H * W;
    const int B = in_sizes[0] / (3 * N * C);
    const int Gh = H / WS, Gw = W / WS;

    dim3 grid(B * Gh * Gw, NH);
    win_attn_lepe<<<grid, 64, 0, stream>>>(qkv, lw, lb, out, B, H, W, C);
}

// Round 3
// 252.114 us; speedup vs baseline: 1.1493x; 1.1493x over previous
//
#include <hip/hip_runtime.h>

#define WS   7
#define NH   8
#define HD   32          // head dim
#define WIN  49          // WS*WS
#define HALO 9           // WS + 2
#define VHST 34          // halo pixel stride in HALFS: bank=(17p+d/2)%32 -> ~2-way max, 4B aligned

typedef __fp16 h2 __attribute__((ext_vector_type(2)));
typedef __fp16 h4 __attribute__((ext_vector_type(4)));
typedef __fp16 h8 __attribute__((ext_vector_type(8)));

__global__ __launch_bounds__(64)
void win_attn_lepe(const float* __restrict__ qkv,
                   const float* __restrict__ lw,
                   const float* __restrict__ lb,
                   float* __restrict__ out,
                   int B, int H, int W, int C)
{
    const int N  = H * W;
    const int Gw = W / WS;
    const int Gh = H / WS;

    const int wid = blockIdx.x;          // window id in [0, B*Gh*Gw)
    const int h   = blockIdx.y;          // head
    const int b   = wid / (Gh * Gw);
    const int g   = wid % (Gh * Gw);
    const int gy  = g / Gw, gx = g % Gw;
    const int row0 = gy * WS, col0 = gx * WS;
    const int c0   = h * HD;

    const size_t plane = (size_t)B * N * C;
    const float* q_base = qkv + (size_t)b * N * C;
    const float* k_base = q_base + plane;
    const float* v_base = q_base + 2 * plane;

    __shared__ __fp16 sK [WIN * HD];          // [49][32], 64B/pixel -> b128 uniform reads
    __shared__ __fp16 sVw[WIN * HD];          // [49][32] window V for PV
    __shared__ __fp16 sVh[HALO * HALO * VHST];// [81][34] halo V for lepe
    __shared__ __fp16 sW [9 * HD];            // [tap][32] lepe weights, tap-major
    __shared__ float  sB [HD];

    const int tid = threadIdx.x;

    // ---- stage K window as f16 ----
    for (int idx = tid; idx < WIN * 8; idx += 64) {
        int n  = idx >> 3;
        int d4 = (idx & 7) * 4;
        int r = row0 + n / WS, c = col0 + n % WS;
        float4 f = *reinterpret_cast<const float4*>(k_base + ((size_t)r * W + c) * C + c0 + d4);
        h2 a  = __builtin_amdgcn_cvt_pkrtz(f.x, f.y);
        h2 bb = __builtin_amdgcn_cvt_pkrtz(f.z, f.w);
        h4 v4 = { a.x, a.y, bb.x, bb.y };
        *reinterpret_cast<h4*>(&sK[n * HD + d4]) = v4;   // byte 64n+2*d4, 8B aligned
    }

    // ---- stage V halo (f16) + duplicate window region into sVw ----
    for (int idx = tid; idx < HALO * HALO * 8; idx += 64) {
        int p  = idx >> 3;
        int d4 = (idx & 7) * 4;
        int py = p / HALO, px = p % HALO;
        int ry = row0 - 1 + py, rx = col0 - 1 + px;
        bool in = (ry >= 0 && ry < H && rx >= 0 && rx < W);
        float4 f = make_float4(0.f, 0.f, 0.f, 0.f);
        if (in) f = *reinterpret_cast<const float4*>(v_base + ((size_t)ry * W + rx) * C + c0 + d4);
        h2 a  = __builtin_amdgcn_cvt_pkrtz(f.x, f.y);
        h2 bb = __builtin_amdgcn_cvt_pkrtz(f.z, f.w);
        *reinterpret_cast<h2*>(&sVh[p * VHST + d4])     = a;   // 4B aligned b32 writes
        *reinterpret_cast<h2*>(&sVh[p * VHST + d4 + 2]) = bb;
        if (py >= 1 && py <= WS && px >= 1 && px <= WS) {
            int m = (py - 1) * WS + (px - 1);
            h4 v4 = { a.x, a.y, bb.x, bb.y };
            *reinterpret_cast<h4*>(&sVw[m * HD + d4]) = v4;
        }
    }

    // ---- stage lepe weights (tap-major) + bias ----
    for (int i = tid; i < HD * 9; i += 64) {
        int d = i / 9, t = i % 9;
        sW[t * HD + d] = (__fp16)lw[(size_t)(c0 + d) * 9 + t];
    }
    if (tid < HD) sB[tid] = lb[c0 + tid];

    __syncthreads();

    if (tid < WIN) {
        const int wy = tid / WS, wx = tid % WS;
        const int r = row0 + wy, c = col0 + wx;

        // q -> f16 pairs in registers, pre-scaled
        const float scale = 0.17677669529663687f;   // 32^-0.5
        h2 qh[16];
        const float* qp = q_base + ((size_t)r * W + c) * C + c0;
        #pragma unroll
        for (int d4 = 0; d4 < 8; ++d4) {
            float4 f = *reinterpret_cast<const float4*>(qp + d4 * 4);
            qh[2 * d4]     = __builtin_amdgcn_cvt_pkrtz(f.x * scale, f.y * scale);
            qh[2 * d4 + 1] = __builtin_amdgcn_cvt_pkrtz(f.z * scale, f.w * scale);
        }

        // scores via v_dot2_f32_f16 (fp32 accumulate); sK reads wave-uniform broadcast
        float s[WIN];
        #pragma unroll
        for (int m = 0; m < WIN; ++m) {
            const h8* kr = reinterpret_cast<const h8*>(&sK[m * HD]);
            float acc = 0.f;
            #pragma unroll
            for (int j = 0; j < 4; ++j) {
                h8 kv = kr[j];
                h2 k0 = { kv[0], kv[1] }, k1 = { kv[2], kv[3] };
                h2 k2 = { kv[4], kv[5] }, k3 = { kv[6], kv[7] };
                acc = __builtin_amdgcn_fdot2(qh[4 * j + 0], k0, acc, false);
                acc = __builtin_amdgcn_fdot2(qh[4 * j + 1], k1, acc, false);
                acc = __builtin_amdgcn_fdot2(qh[4 * j + 2], k2, acc, false);
                acc = __builtin_amdgcn_fdot2(qh[4 * j + 3], k3, acc, false);
            }
            s[m] = acc;
        }

        // softmax (lane-local, fp32)
        float mx = s[0];
        #pragma unroll
        for (int m = 1; m < WIN; ++m) mx = fmaxf(mx, s[m]);
        float sum = 0.f;
        #pragma unroll
        for (int m = 0; m < WIN; ++m) { s[m] = __expf(s[m] - mx); sum += s[m]; }
        const float inv = 1.f / sum;

        // out = P @ V, fp32 accumulate via v_fma_mix (float += float * (float)half)
        float o[HD];
        #pragma unroll
        for (int d = 0; d < HD; ++d) o[d] = 0.f;
        #pragma unroll
        for (int m = 0; m < WIN; ++m) {
            float pf = s[m] * inv;
            const h8* vr = reinterpret_cast<const h8*>(&sVw[m * HD]);
            #pragma unroll
            for (int j = 0; j < 4; ++j) {
                h8 vv = vr[j];
                #pragma unroll
                for (int e = 0; e < 8; ++e)
                    o[j * 8 + e] += pf * (float)vv[e];
            }
        }

        // lepe: depthwise 3x3 + bias, fp32 accumulate
        #pragma unroll
        for (int t = 0; t < 9; ++t) {
            int dh = t / 3, dw = t % 3;
            const __fp16* vb = &sVh[((wy + dh) * HALO + (wx + dw)) * VHST];
            const __fp16* wb = &sW[t * HD];
            #pragma unroll
            for (int d2 = 0; d2 < 16; ++d2) {
                h2 w2 = *reinterpret_cast<const h2*>(&wb[2 * d2]);   // uniform
                h2 v2 = *reinterpret_cast<const h2*>(&vb[2 * d2]);   // ~2-way banks
                o[2 * d2]     += (float)w2.x * (float)v2.x;
                o[2 * d2 + 1] += (float)w2.y * (float)v2.y;
            }
        }

        // write out[b, r*W+c, c0..c0+31]
        float* dst = out + ((size_t)b * N + (size_t)r * W + c) * C + c0;
        #pragma unroll
        for (int d4 = 0; d4 < 8; ++d4) {
            float4 t4 = make_float4(o[4 * d4] + sB[4 * d4],
                                    o[4 * d4 + 1] + sB[4 * d4 + 1],
                                    o[4 * d4 + 2] + sB[4 * d4 + 2],
                                    o[4 * d4 + 3] + sB[4 * d4 + 3]);
            *reinterpret_cast<float4*>(dst + d4 * 4) = t4;
        }
    }
}

extern "C" void kernel_launch(void* const* d_in, const int* in_sizes, int n_in,
                              void* d_out, int out_size, void* d_ws, size_t ws_size,
                              hipStream_t stream) {
    const float* qkv = (const float*)d_in[0];
    const float* lw  = (const float*)d_in[1];
    const float* lb  = (const float*)d_in[2];
    float* out = (float*)d_out;

    const int H = 112, W = 112;
    const int C = in_sizes[2];                 // lepe_b has C elements
    const int N = H * W;
    const int B = in_sizes[0] / (3 * N * C);
    const int Gh = H / WS, Gw = W / WS;

    dim3 grid(B * Gh * Gw, NH);
    win_attn_lepe<<<grid, 64, 0, stream>>>(qkv, lw, lb, out, B, H, W, C);
}